// Round 7
// baseline (293.730 us; speedup 1.0000x reference)
//
#include <hip/hip_runtime.h>
#include <hip/hip_bf16.h>

typedef __bf16 bf16_t;
typedef bf16_t bf16x8 __attribute__((ext_vector_type(8)));
typedef float floatx4 __attribute__((ext_vector_type(4)));

#define MFMA16(a, b, c) __builtin_amdgcn_mfma_f32_16x16x32_bf16((a), (b), (c), 0, 0, 0)

// ---------------------------------------------------------------------------
// One-time weight convert fp32 -> bf16, PRE-SWIZZLED into MFMA fragment order.
// QKV region (wb[0..196607]): 48 col16-chunks x 8 k. chunk = c*8 + k
//   (c in [0,48), k in [0,8)), 512 bf16/chunk at offset chunk*512 + lane*8.
//   Element (lane,d) = w_qkv[(c*16 + (lane&15))*256 + k*32 + (lane>>4)*8 + d].
// PROJ region (wb[196608..262143]): 8 panels of 32 cols. chunk = p*16+k*2+j
//   Element (lane,d) = w_proj[(p*32+j*16+(lane&15))*256 + k*32 + (lane>>4)*8+d].
// ---------------------------------------------------------------------------
__global__ __launch_bounds__(256) void wconv_kernel(
    const float* __restrict__ w_qkv, const float* __restrict__ w_proj,
    bf16_t* __restrict__ wb)
{
  int i = blockIdx.x * 256 + threadIdx.x;      // 0 .. 32767, one 16B chunk each
  const float* src;
  bf16_t* dst;
  if (i < 24576) {                             // qkv: 384 chunks x 64 lanes
    int chunk = i >> 6, l = i & 63;
    int c = chunk >> 3, k = chunk & 7;
    int col = c * 16 + (l & 15);
    int kk = k * 32 + (l >> 4) * 8;
    src = w_qkv + col * 256 + kk;
    dst = wb + (i << 3);
  } else {                                     // proj: 128 chunks x 64 lanes
    int ip = i - 24576;
    int chunk = ip >> 6, l = ip & 63;
    int p = chunk >> 4, rem = chunk & 15, k = rem >> 1, j = rem & 1;
    int col = p * 32 + j * 16 + (l & 15);
    int kk = k * 32 + (l >> 4) * 8;
    src = w_proj + col * 256 + kk;
    dst = wb + 196608 + (ip << 3);
  }
  float4 f0 = ((const float4*)src)[0];
  float4 f1 = ((const float4*)src)[1];
  bf16_t t8[8] = {(bf16_t)f0.x, (bf16_t)f0.y, (bf16_t)f0.z, (bf16_t)f0.w,
                  (bf16_t)f1.x, (bf16_t)f1.y, (bf16_t)f1.z, (bf16_t)f1.w};
  *(uint4*)dst = *(const uint4*)t8;
}

__device__ __forceinline__ void cvt8_store(bf16_t* dst, float4 f0, float4 f1) {
  bf16_t t8[8] = {(bf16_t)f0.x, (bf16_t)f0.y, (bf16_t)f0.z, (bf16_t)f0.w,
                  (bf16_t)f1.x, (bf16_t)f1.y, (bf16_t)f1.z, (bf16_t)f1.w};
  *(uint4*)dst = *(const uint4*)t8;
}

// ---------------------------------------------------------------------------
// Kernel 1: per-token attention, 32-token tiles (grid 3136), 512 thr.
// P0 stage X -> b0 -> P1 ONE QKV gemm (wave owns 96 cols, 12 MFMA/k-step)
// -> b1 -> write Q,K->QK, V->Xs (X dead) -> b2 -> P2 softmax on ALL 512
// threads (task (t,h,half-d), shfl_xor combine; p -> Pl f16) -> b3 ->
// P3 PV on ALL 512 threads (task (t,j): 4 col-chunks share each V float4).
// LDS 54.3 KB -> 3 blocks/CU.
// ---------------------------------------------------------------------------
#define XS_S 264   // row stride (bf16) for Xs: 528B, 16B-aligned
#define QK_S 520   // row stride (bf16) for QK: 1040B, 16B-aligned

__global__ __launch_bounds__(512, 4) void attn_kernel(
    const float* __restrict__ x,
    const bf16_t* __restrict__ wb,
    float* __restrict__ outf,
    bf16_t* __restrict__ preb)          // non-null: write pre as bf16 here
{
  __shared__ __align__(16) bf16_t Xs[32][XS_S];     // 16.5 KB  X tile, then V
  __shared__ __align__(16) bf16_t QK[32][QK_S];     // 32.5 KB  Q|K
  __shared__ __align__(16) _Float16 Pl[32][8][8];   //  4.0 KB  probs

  const int tid = threadIdx.x;
  const int wave = tid >> 6, lane = tid & 63, quad = lane >> 4, l16 = lane & 15;
  const long base = (long)blockIdx.x * 32;
  const float scale = 0.17677669529663687f;       // 32^-0.5

  // ---- P0: stage X: 32x256 fp32 -> bf16 LDS, fully coalesced ----
  const float* xb = x + base * 256;
#pragma unroll
  for (int it = 0; it < 2; ++it) {
    int idx = tid + it * 512;
    int s = idx >> 5, g = (idx & 31) * 8;
    const float* p = xb + s * 256 + g;
    float4 f0 = ((const float4*)p)[0];
    float4 f1 = ((const float4*)p)[1];
    cvt8_store(&Xs[s][g], f0, f1);
  }
  __syncthreads();   // b0

  // ---- P1: QKV gemm [32x768] = X @ Wqkv^T; wave owns cols wave*96..+96 ----
  floatx4 acc[2][6];
#pragma unroll
  for (int i = 0; i < 2; ++i)
#pragma unroll
    for (int j = 0; j < 6; ++j) acc[i][j] = (floatx4){0.f, 0.f, 0.f, 0.f};
  {
    // swizzled chunk for (wave, j, k): ((wave*6 + j)*8 + k) * 512 + lane*8
    auto loadB6 = [&](bf16x8 (&dst)[6], int k) {
      const bf16_t* cb = wb + ((long)(wave * 48 + k) << 9) + lane * 8;
#pragma unroll
      for (int j = 0; j < 6; ++j) dst[j] = *(const bf16x8*)(cb + (j << 12));
    };
    bf16x8 Ba[6], Bb[6];
    loadB6(Ba, 0);
#pragma unroll
    for (int k = 0; k < 8; ++k) {
      const bf16x8* cur = (k & 1) ? Bb : Ba;
      if (k < 7) loadB6((k & 1) ? Ba : Bb, k + 1);
      bf16x8 A0 = *(const bf16x8*)(&Xs[l16][k * 32 + quad * 8]);
      bf16x8 A1 = *(const bf16x8*)(&Xs[16 + l16][k * 32 + quad * 8]);
#pragma unroll
      for (int j = 0; j < 6; ++j) {
        acc[0][j] = MFMA16(A0, cur[j], acc[0][j]);
        acc[1][j] = MFMA16(A1, cur[j], acc[1][j]);
      }
    }
  }
  __syncthreads();   // b1: all X reads done (Xs can be overwritten by V)

  // ---- write Q,K -> QK; V -> Xs ----
#pragma unroll
  for (int j = 0; j < 6; ++j) {
    int g = wave * 96 + j * 16 + l16;
#pragma unroll
    for (int i = 0; i < 2; ++i)
#pragma unroll
      for (int r = 0; r < 4; ++r) {
        int row = i * 16 + quad * 4 + r;
        if (g < 512) QK[row][g] = (bf16_t)acc[i][j][r];
        else         Xs[row][g - 512] = (bf16_t)acc[i][j][r];
      }
  }
  __syncthreads();   // b2: Q,K,V visible

  // ---- P2: softmax on ALL 512 threads. task = (t, h, sg half-of-d) ----
  {
    const int t = tid >> 4, h = (tid >> 1) & 7, sg = tid & 1;
    const bf16_t* qrow = &QK[t][h * 32 + sg * 16];
    float qf[16];
    {
      bf16x8 q0 = *(const bf16x8*)(qrow);
      bf16x8 q1 = *(const bf16x8*)(qrow + 8);
#pragma unroll
      for (int d = 0; d < 8; ++d) { qf[d] = (float)q0[d]; qf[8 + d] = (float)q1[d]; }
    }
    float sc[8];
#pragma unroll
    for (int e = 0; e < 8; ++e) {
      const bf16_t* krow = &QK[t][256 + e * 32 + sg * 16];
      bf16x8 k0 = *(const bf16x8*)(krow);
      bf16x8 k1 = *(const bf16x8*)(krow + 8);
      float a = 0.f;
#pragma unroll
      for (int d = 0; d < 8; ++d) a += qf[d] * (float)k0[d] + qf[8 + d] * (float)k1[d];
      sc[e] = a;
    }
#pragma unroll
    for (int e = 0; e < 8; ++e) sc[e] += __shfl_xor(sc[e], 1);
    float mx = -INFINITY;
#pragma unroll
    for (int e = 0; e < 8; ++e) { sc[e] *= scale; mx = fmaxf(mx, sc[e]); }
    float sum = 0.f, pv[8];
#pragma unroll
    for (int e = 0; e < 8; ++e) { pv[e] = __expf(sc[e] - mx); sum += pv[e]; }
    float rs = 1.0f / sum;
    if (sg == 0) {
      _Float16 ph[8];
#pragma unroll
      for (int e = 0; e < 8; ++e) ph[e] = (_Float16)(pv[e] * rs);
      *(uint4*)(&Pl[t][h][0]) = *(const uint4*)ph;
    }
  }
  __syncthreads();   // b3: Pl ready

  // ---- P3: PV on ALL 512 threads. task (t,j): output cols j*4 + m*64,
  //      m=0..3; all 4 chunks share V[t][e*32 + (j&7)*4 .. +4] ----
  {
    const int t = tid >> 4, j = tid & 15, j8 = j & 7, h0 = j >> 3;
    float pf[4][8];
#pragma unroll
    for (int m = 0; m < 4; ++m) {
      _Float16 ph[8];
      *(uint4*)ph = *(const uint4*)(&Pl[t][h0 + 2 * m][0]);
#pragma unroll
      for (int e = 0; e < 8; ++e) pf[m][e] = (float)ph[e];
    }
    float pr[4][4];
#pragma unroll
    for (int m = 0; m < 4; ++m)
#pragma unroll
      for (int d = 0; d < 4; ++d) pr[m][d] = 0.f;
#pragma unroll
    for (int e = 0; e < 8; ++e) {
      bf16_t v4[4];
      *(uint2*)v4 = *(const uint2*)(&Xs[t][e * 32 + j8 * 4]);
      float vf[4];
#pragma unroll
      for (int d = 0; d < 4; ++d) vf[d] = (float)v4[d];
#pragma unroll
      for (int m = 0; m < 4; ++m) {
        float pe = pf[m][e];
#pragma unroll
        for (int d = 0; d < 4; ++d) pr[m][d] += pe * vf[d];
      }
    }
    if (preb) {
      bf16_t* op = preb + (base + t) * 256 + j * 4;
#pragma unroll
      for (int m = 0; m < 4; ++m) {
        bf16_t o4[4] = {(bf16_t)pr[m][0], (bf16_t)pr[m][1],
                        (bf16_t)pr[m][2], (bf16_t)pr[m][3]};
        *(uint2*)(op + m * 64) = *(const uint2*)o4;
      }
    } else {
      float* op = outf + (base + t) * 256 + j * 4;
#pragma unroll
      for (int m = 0; m < 4; ++m) {
        float4 f = {pr[m][0], pr[m][1], pr[m][2], pr[m][3]};
        *(float4*)(op + m * 64) = f;
      }
    }
  }
}

// ---------------------------------------------------------------------------
// Kernel 2: LDS-free scrambled projection (grid 2048, 512 thr, no barriers).
// out(49x256) = Sc @ Wp^T + bias where Sc[s'][c'] = preflat[s'*256+c'],
// flat = h*1568 + s*32 + d. Every 8-elem A-fragment (c' = k*32+quad*8) is a
// CONTIGUOUS 8-run of preb (chunks never cross h/s boundaries: 1568%32==0),
// so A loads directly from global with inverse-scramble index math:
//   q5 = mr*8 + k; h = q5/49; s = q5-h*49; addr-row = rowbase+(s/7)*56+s%7.
// B streams from the swizzled proj region (contiguous wave-reads).
// ---------------------------------------------------------------------------
__global__ __launch_bounds__(512, 4) void proj_kernel(
    const bf16_t* __restrict__ wb,
    const float* __restrict__ b_proj,
    float* __restrict__ out,
    const bf16_t* __restrict__ preb)
{
  const int n = blockIdx.x;              // window id 0..2047
  const int b = n >> 6, wh = (n >> 3) & 7, ww = n & 7;
  const int rowbase = b * 3136 + wh * 392 + ww * 7;
  const int tid = threadIdx.x;
  const int wave = tid >> 6, lane = tid & 63, quad = lane >> 4, l16 = lane & 15;

  // B dbuf from swizzled proj region: chunk = wave*16 + k*2 + j
  auto loadBp = [&](bf16x8 (&dst)[2], int k) {
#pragma unroll
    for (int j = 0; j < 2; ++j)
      dst[j] = *(const bf16x8*)(wb + 196608 +
          ((long)(wave * 16 + k * 2 + j) << 9) + lane * 8);
  };
  // A fragment loader: 4 M-tiles, k compile-time via unroll
  auto loadA = [&](bf16x8 (&dst)[4], int k) {
#pragma unroll
    for (int i = 0; i < 4; ++i) {
      int mr = i * 16 + l16; if (mr > 48) mr = 48;
      int q5 = mr * 8 + k;                 // 0..391
      int h = q5 / 49;
      int s = q5 - h * 49;
      int srow = (s / 7) * 56 + (s - (s / 7) * 7);
      dst[i] = *(const bf16x8*)(preb + (long)(rowbase + srow) * 256 +
                                h * 32 + quad * 8);
    }
  };

  const float bv0 = b_proj[wave * 32 + l16];
  const float bv1 = b_proj[wave * 32 + 16 + l16];

  floatx4 acc[4][2];
#pragma unroll
  for (int i = 0; i < 4; ++i)
#pragma unroll
    for (int j = 0; j < 2; ++j) acc[i][j] = (floatx4){0.f, 0.f, 0.f, 0.f};

  bf16x8 Aa[4], Ab[4], Ba[2], Bb[2];
  loadA(Aa, 0); loadBp(Ba, 0);
#pragma unroll
  for (int k = 0; k < 8; ++k) {
    const bf16x8* cA = (k & 1) ? Ab : Aa;
    const bf16x8* cB = (k & 1) ? Bb : Ba;
    if (k < 7) { loadA((k & 1) ? Aa : Ab, k + 1); loadBp((k & 1) ? Ba : Bb, k + 1); }
#pragma unroll
    for (int i = 0; i < 4; ++i) {
      acc[i][0] = MFMA16(cA[i], cB[0], acc[i][0]);
      acc[i][1] = MFMA16(cA[i], cB[1], acc[i][1]);
    }
  }
#pragma unroll
  for (int i = 0; i < 4; ++i)
#pragma unroll
    for (int r = 0; r < 4; ++r) {
      int m = i * 16 + quad * 4 + r;
      if (m < 49) {
        int srow = (m / 7) * 56 + (m - (m / 7) * 7);
        float* orow = out + (long)(rowbase + srow) * 256 + wave * 32 + l16;
        orow[0]  = acc[i][0][r] + bv0;
        orow[16] = acc[i][1][r] + bv1;
      }
    }
}

// ---------------------------------------------------------------------------
// Fallback proj (fp32 in-place on out via LDS), when workspace too small.
// ---------------------------------------------------------------------------
#define SC_S 264
__global__ __launch_bounds__(512, 4) void proj_fallback(
    const bf16_t* __restrict__ wb,
    const float* __restrict__ b_proj,
    float* out)
{
  __shared__ __align__(16) bf16_t Sc[49][SC_S];
  __shared__ int trow[49];
  const int n = blockIdx.x;
  const int b = n >> 6, wh = (n >> 3) & 7, ww = n & 7;
  const int tid = threadIdx.x;
  const int wave = tid >> 6, lane = tid & 63, quad = lane >> 4, l16 = lane & 15;

  auto loadBp = [&](bf16x8 (&dst)[2], int k) {
#pragma unroll
    for (int j = 0; j < 2; ++j)
      dst[j] = *(const bf16x8*)(wb + 196608 +
          ((long)(wave * 16 + k * 2 + j) << 9) + lane * 8);
  };
  const float bv0 = b_proj[wave * 32 + l16];
  const float bv1 = b_proj[wave * 32 + 16 + l16];

  if (tid < 49) {
    int i = tid / 7, j = tid % 7;
    trow[tid] = b * 3136 + (wh * 7 + i) * 56 + ww * 7 + j;
  }
  __syncthreads();
  for (int idx = tid; idx < 49 * 32; idx += 512) {
    int s = idx >> 5, c8 = idx & 31;
    const float* p = out + (long)trow[s] * 256 + c8 * 8;
    float4 f0 = ((const float4*)p)[0];
    float4 f1 = ((const float4*)p)[1];
    int flat = (c8 >> 2) * 1568 + s * 32 + (c8 & 3) * 8;
    cvt8_store(&Sc[flat >> 8][flat & 255], f0, f1);
  }
  __syncthreads();
  floatx4 acc[4][2];
#pragma unroll
  for (int i = 0; i < 4; ++i)
#pragma unroll
    for (int j = 0; j < 2; ++j) acc[i][j] = (floatx4){0.f, 0.f, 0.f, 0.f};
  bf16x8 Aa[4], Ab[4], Ba[2], Bb[2];
  auto loadA = [&](bf16x8* dst, int k) {
#pragma unroll
    for (int i = 0; i < 4; ++i) {
      int mr = i * 16 + l16; if (mr > 48) mr = 48;
      dst[i] = *(const bf16x8*)(&Sc[mr][k * 32 + quad * 8]);
    }
  };
  loadA(Aa, 0); loadBp(Ba, 0);
#pragma unroll
  for (int k = 0; k < 8; ++k) {
    const bf16x8* cA = (k & 1) ? Ab : Aa;
    const bf16x8* cB = (k & 1) ? Bb : Ba;
    if (k < 7) { loadA((k & 1) ? Aa : Ab, k + 1); loadBp((k & 1) ? Ba : Bb, k + 1); }
#pragma unroll
    for (int i = 0; i < 4; ++i) {
      acc[i][0] = MFMA16(cA[i], cB[0], acc[i][0]);
      acc[i][1] = MFMA16(cA[i], cB[1], acc[i][1]);
    }
  }
#pragma unroll
  for (int i = 0; i < 4; ++i)
#pragma unroll
    for (int r = 0; r < 4; ++r) {
      int m = i * 16 + quad * 4 + r;
      if (m < 49) {
        float* orow = out + (long)trow[m] * 256 + wave * 32 + l16;
        orow[0]  = acc[i][0][r] + bv0;
        orow[16] = acc[i][1][r] + bv1;
      }
    }
}

// ---------------------------------------------------------------------------
extern "C" void kernel_launch(void* const* d_in, const int* in_sizes, int n_in,
                              void* d_out, int out_size, void* d_ws, size_t ws_size,
                              hipStream_t stream) {
  (void)in_sizes; (void)n_in; (void)out_size;
  const float* x      = (const float*)d_in[0];
  const float* w_qkv  = (const float*)d_in[1];
  const float* w_proj = (const float*)d_in[2];
  const float* b_proj = (const float*)d_in[3];
  float* out = (float*)d_out;
  bf16_t* wb = (bf16_t*)d_ws;   // 262144 bf16 = 512 KB

  // bf16 pre buffer (100352*256*2 = 51.4 MB) if workspace allows
  bf16_t* preb = nullptr;
  if (ws_size >= (size_t)524288 + 51380224) preb = wb + 262144;

  wconv_kernel<<<dim3(128), 256, 0, stream>>>(w_qkv, w_proj, wb);
  attn_kernel<<<dim3(3136), 512, 0, stream>>>(x, wb, out, preb);
  if (preb)
    proj_kernel<<<dim3(2048), 512, 0, stream>>>(wb, b_proj, out, preb);
  else
    proj_fallback<<<dim3(2048), 512, 0, stream>>>(wb, b_proj, out);
}